// Round 1
// baseline (187.065 us; speedup 1.0000x reference)
//
#include <hip/hip_runtime.h>

#define G_    32
#define N_    128
#define NP1_  129
#define H_    32
#define EAD_  16
#define MAXD_ 5
#define NE_   65536
#define NPTH_ 1048576

// ---------------------------------------------------------------------------
// Kernel 1: edge encoder + scatter into dense_adj [G][N][N][H]
// one thread per (edge, head); 32 consecutive threads write 128B contiguous.
// ---------------------------------------------------------------------------
__global__ __launch_bounds__(256) void edge_scatter_kernel(
    const float* __restrict__ edge_attr,    // [NE][16]
    const int*   __restrict__ edge_index,   // [3][NE]
    const float* __restrict__ edge_enc_w,   // [H][16]
    float*       __restrict__ dense_adj) {  // [G][N][N][H]
  int t = blockIdx.x * blockDim.x + threadIdx.x;
  if (t >= NE_ * H_) return;
  int e = t >> 5;
  int h = t & 31;
  const float* ea = edge_attr + e * EAD_;
  const float* w  = edge_enc_w + h * EAD_;
  float s = 0.f;
#pragma unroll
  for (int k = 0; k < EAD_; ++k) s += ea[k] * w[k];
  int g = edge_index[e];
  int i = edge_index[NE_ + e];
  int j = edge_index[2 * NE_ + e];
  dense_adj[(((g * N_) + i) * N_ + j) * H_ + h] = s;
}

// ---------------------------------------------------------------------------
// Kernel 2: path gather + per-distance head mixing + atomic accumulate
// 32 lanes per path: lane k computes output head k.
// Rows that are entirely zero (87.5% of gathers) are skipped exactly.
// ---------------------------------------------------------------------------
__global__ __launch_bounds__(256) void path_accum_kernel(
    const int*   __restrict__ path_index,   // [6][NPTH]
    const float* __restrict__ dense_adj,    // [G][N][N][H]
    const float* __restrict__ Wdis,         // edge_dis_emb flat [d][h][k]
    float*       __restrict__ acc) {        // [G][N][N][H]
  int lane = threadIdx.x & 31;
  int p = (blockIdx.x * blockDim.x + threadIdx.x) >> 5;
  if (p >= NPTH_) return;

  int pg = path_index[p];
  int pi = path_index[NPTH_ + p];
  int pj = path_index[2 * NPTH_ + p];
  int pd = path_index[3 * NPTH_ + p];
  int ps = path_index[4 * NPTH_ + p];
  int pt = path_index[5 * NPTH_ + p];

  const float* row = dense_adj + (((pg * N_) + ps) * N_ + pt) * H_;
  float rv = row[lane];                         // coalesced 128B per group

  unsigned long long b = __ballot(rv != 0.0f);
  unsigned long long gm = (threadIdx.x & 32) ? 0xFFFFFFFF00000000ull
                                             : 0x00000000FFFFFFFFull;
  if ((b & gm) == 0) return;                    // zero row -> zero contribution

  int base = threadIdx.x & 32;                  // group base within the wave64
  const float* Wd = Wdis + pd * H_ * H_;
  float v = 0.f;
#pragma unroll
  for (int h = 0; h < H_; ++h) {
    float rh = __shfl(rv, base + h, 64);        // source lane within own group
    v += rh * Wd[h * H_ + lane];                // coalesced, L1-resident 20KB
  }
  atomicAdd(&acc[(((pg * N_) + pi) * N_ + pj) * H_ + lane], v);
}

// ---------------------------------------------------------------------------
// Kernel 3: final assembly. One block per (g, a) output row.
// out[g][h][a][b] = 2*attn_bias[g][a][b]
//   + (a==0 || b==0) ? virt[h]
//   : spe[spatial_pos[g][a-1][b-1]][h] + acc[g][a-1][b-1][h] / sp_norm
// ---------------------------------------------------------------------------
__global__ __launch_bounds__(256) void output_kernel(
    const float* __restrict__ attn_bias,    // [G][129][129]
    const int*   __restrict__ spatial_pos,  // [G][N][N]
    const float* __restrict__ spe,          // [512][H]
    const float* __restrict__ virt,         // [H]
    const float* __restrict__ acc,          // [G][N][N][H]
    float*       __restrict__ out) {        // [G][H][129][129]
  __shared__ float lds_acc[N_ * 33];        // padded: conflict-free transpose
  __shared__ float lds_inv[N_];
  __shared__ int   lds_sp[N_];
  __shared__ float lds_virt[H_];

  int blk = blockIdx.x;
  int g = blk / NP1_;
  int a = blk - g * NP1_;
  int tid = threadIdx.x;

  if (tid < H_) lds_virt[tid] = virt[tid];

  const float* ab = attn_bias + (g * NP1_ + a) * NP1_;

  if (a == 0) {
    __syncthreads();
    for (int t = tid; t < H_ * NP1_; t += 256) {
      int h = t / NP1_;
      int b = t - h * NP1_;
      out[((g * H_ + h) * NP1_) * NP1_ + b] = 2.f * ab[b] + lds_virt[h];
    }
    return;
  }

  int i = a - 1;
  // stage acc row (4096 contiguous floats) into padded LDS
  const float* acc_row = acc + ((g * N_ + i) * N_) * H_;
  for (int t = tid; t < N_ * H_; t += 256) {
    int j = t >> 5;
    int h = t & 31;
    lds_acc[j * 33 + h] = acc_row[t];
  }
  // stage spatial_pos row + normalizer
  if (tid < N_) {
    int s = spatial_pos[(g * N_ + i) * N_ + tid];
    lds_sp[tid] = s;
    int s2 = (s == 0) ? 1 : s;
    s2 = (s2 > 1) ? s2 - 1 : s2;
    s2 = (s2 > MAXD_) ? MAXD_ : s2;
    lds_inv[tid] = 1.0f / (float)s2;
  }
  __syncthreads();

  for (int t = tid; t < H_ * NP1_; t += 256) {
    int h = t / NP1_;
    int b = t - h * NP1_;
    float val = 2.f * ab[b];
    if (b == 0) {
      val += lds_virt[h];
    } else {
      int j = b - 1;
      val += spe[lds_sp[j] * H_ + h] + lds_acc[j * 33 + h] * lds_inv[j];
    }
    out[((g * H_ + h) * NP1_ + a) * NP1_ + b] = val;
  }
}

// ---------------------------------------------------------------------------
extern "C" void kernel_launch(void* const* d_in, const int* in_sizes, int n_in,
                              void* d_out, int out_size, void* d_ws, size_t ws_size,
                              hipStream_t stream) {
  const float* attn_bias   = (const float*)d_in[0];
  const int*   spatial_pos = (const int*)d_in[1];
  const int*   edge_index  = (const int*)d_in[2];
  const float* edge_attr   = (const float*)d_in[3];
  const int*   path_index  = (const int*)d_in[4];
  const float* edge_enc_w  = (const float*)d_in[5];
  const float* spe         = (const float*)d_in[6];
  const float* virt        = (const float*)d_in[7];
  const float* edge_dis    = (const float*)d_in[8];
  float* out = (float*)d_out;

  const size_t DENSE_ELEMS = (size_t)G_ * N_ * N_ * H_;   // 16.7M floats, 64MB
  float* dense_adj = (float*)d_ws;
  float* acc       = dense_adj + DENSE_ELEMS;

  // zero dense_adj + acc (128 MB) every call -> deterministic
  hipMemsetAsync(d_ws, 0, 2 * DENSE_ELEMS * sizeof(float), stream);

  // edge encoder + scatter
  {
    int total = NE_ * H_;
    edge_scatter_kernel<<<(total + 255) / 256, 256, 0, stream>>>(
        edge_attr, edge_index, edge_enc_w, dense_adj);
  }
  // path accumulate
  {
    long long total = (long long)NPTH_ * 32;
    path_accum_kernel<<<(int)((total + 255) / 256), 256, 0, stream>>>(
        path_index, dense_adj, edge_dis, acc);
  }
  // final output
  output_kernel<<<G_ * NP1_, 256, 0, stream>>>(
      attn_bias, spatial_pos, spe, virt, acc, out);
}